// Round 5
// baseline (325.120 us; speedup 1.0000x reference)
//
#include <hip/hip_runtime.h>

#define NFREQ 2049   // 4096/2 + 1

using cf = float2;
typedef __attribute__((ext_vector_type(8))) short short8;
typedef __attribute__((ext_vector_type(4))) float floatx4;

__device__ inline unsigned short bf16_rne(float x) {
  unsigned u = __float_as_uint(x);
  unsigned r = u + 0x7FFFu + ((u >> 16) & 1u);
  return (unsigned short)(r >> 16);
}
__device__ inline float bf16_to_f(unsigned short h) {
  return __uint_as_float(((unsigned)h) << 16);
}

// ---------------------------------------------------------------------------
// K1: projection GEMM  C = X @ W^T + b  via split-bf16 MFMA (3 passes).
// ---------------------------------------------------------------------------
__global__ __launch_bounds__(256, 4) void gemm_proj(
    const float* __restrict__ X, const float* __restrict__ W,
    const float* __restrict__ bias, float* __restrict__ dst, int mode)
{
  __shared__ __align__(16) unsigned short sm[12416];
  unsigned short* sAhi = sm;            // 4*129*8 = 4128
  unsigned short* sAlo = sm + 4128;
  unsigned short* sBhi = sm + 8256;     // 4*65*8  = 2080
  unsigned short* sBlo = sm + 10336;

  const int tid = threadIdx.x;
  const int m0 = blockIdx.x * 128;
  const int j0 = blockIdx.y * 64;
  const int wave = tid >> 6, lane = tid & 63;
  const int wm = wave & 1, wj = wave >> 1;
  const int lm = lane & 15, quad = lane >> 4;

  floatx4 acc[4][2] = {};

  for (int k0 = 0; k0 < 256; k0 += 32) {
    float4 xa[4], wb[2];
    #pragma unroll
    for (int r = 0; r < 4; r++) {
      int v = tid + r * 256;
      int row = v >> 3, c4 = (v & 7) * 4;
      xa[r] = *(const float4*)(X + (size_t)(m0 + row) * 256 + k0 + c4);
    }
    #pragma unroll
    for (int r = 0; r < 2; r++) {
      int v = tid + r * 256;
      int row = v >> 3, c4 = (v & 7) * 4;
      wb[r] = *(const float4*)(W + (size_t)(j0 + row) * 256 + k0 + c4);
    }
    __syncthreads();
    #pragma unroll
    for (int r = 0; r < 4; r++) {
      int v = tid + r * 256;
      int row = v >> 3, c4 = (v & 7) * 4;
      int q = c4 >> 3, off = c4 & 7;
      float f[4] = {xa[r].x, xa[r].y, xa[r].z, xa[r].w};
      unsigned short h[4], l[4];
      #pragma unroll
      for (int i = 0; i < 4; i++) {
        h[i] = bf16_rne(f[i]);
        l[i] = bf16_rne(f[i] - bf16_to_f(h[i]));
      }
      int idx = ((q * 129 + row) << 3) + off;
      *(uint2*)&sAhi[idx] = make_uint2((unsigned)h[0] | ((unsigned)h[1] << 16),
                                       (unsigned)h[2] | ((unsigned)h[3] << 16));
      *(uint2*)&sAlo[idx] = make_uint2((unsigned)l[0] | ((unsigned)l[1] << 16),
                                       (unsigned)l[2] | ((unsigned)l[3] << 16));
    }
    #pragma unroll
    for (int r = 0; r < 2; r++) {
      int v = tid + r * 256;
      int row = v >> 3, c4 = (v & 7) * 4;
      int q = c4 >> 3, off = c4 & 7;
      float f[4] = {wb[r].x, wb[r].y, wb[r].z, wb[r].w};
      unsigned short h[4], l[4];
      #pragma unroll
      for (int i = 0; i < 4; i++) {
        h[i] = bf16_rne(f[i]);
        l[i] = bf16_rne(f[i] - bf16_to_f(h[i]));
      }
      int idx = ((q * 65 + row) << 3) + off;
      *(uint2*)&sBhi[idx] = make_uint2((unsigned)h[0] | ((unsigned)h[1] << 16),
                                       (unsigned)h[2] | ((unsigned)h[3] << 16));
      *(uint2*)&sBlo[idx] = make_uint2((unsigned)l[0] | ((unsigned)l[1] << 16),
                                       (unsigned)l[2] | ((unsigned)l[3] << 16));
    }
    __syncthreads();

    short8 ahi[4], alo[4], bhi[2], blo[2];
    #pragma unroll
    for (int mf = 0; mf < 4; mf++) {
      int row = wm * 64 + mf * 16 + lm;
      int idx = ((quad * 129 + row) << 3);
      ahi[mf] = *(const short8*)&sAhi[idx];
      alo[mf] = *(const short8*)&sAlo[idx];
    }
    #pragma unroll
    for (int jf = 0; jf < 2; jf++) {
      int row = wj * 32 + jf * 16 + lm;
      int idx = ((quad * 65 + row) << 3);
      bhi[jf] = *(const short8*)&sBhi[idx];
      blo[jf] = *(const short8*)&sBlo[idx];
    }
    #pragma unroll
    for (int mf = 0; mf < 4; mf++)
      #pragma unroll
      for (int jf = 0; jf < 2; jf++) {
        acc[mf][jf] = __builtin_amdgcn_mfma_f32_16x16x32_bf16(
            ahi[mf], bhi[jf], acc[mf][jf], 0, 0, 0);
        acc[mf][jf] = __builtin_amdgcn_mfma_f32_16x16x32_bf16(
            ahi[mf], blo[jf], acc[mf][jf], 0, 0, 0);
        acc[mf][jf] = __builtin_amdgcn_mfma_f32_16x16x32_bf16(
            alo[mf], bhi[jf], acc[mf][jf], 0, 0, 0);
      }
  }

  #pragma unroll
  for (int jf = 0; jf < 2; jf++) {
    float bj = bias[j0 + wj * 32 + jf * 16 + lm];
    #pragma unroll
    for (int mf = 0; mf < 4; mf++)
      #pragma unroll
      for (int r = 0; r < 4; r++)
        acc[mf][jf][r] += bj;
  }

  if (mode == 2) {
    #pragma unroll
    for (int mf = 0; mf < 4; mf++)
      #pragma unroll
      for (int jf = 0; jf < 2; jf++) {
        int j = j0 + wj * 32 + jf * 16 + lm;
        int mb = m0 + wm * 64 + mf * 16 + quad * 4;
        #pragma unroll
        for (int r = 0; r < 4; r++)
          dst[(size_t)(mb + r) * 256 + j] = acc[mf][jf][r];
      }
  } else {
    const int b = m0 >> 12;
    const int n0 = m0 & 4095;
    #pragma unroll
    for (int mf = 0; mf < 4; mf++)
      #pragma unroll
      for (int jf = 0; jf < 2; jf++) {
        int j = j0 + wj * 32 + jf * 16 + lm;
        int nb = n0 + wm * 64 + mf * 16 + quad * 4;
        float4 o = make_float4(acc[mf][jf][0], acc[mf][jf][1],
                               acc[mf][jf][2], acc[mf][jf][3]);
        *(float4*)(dst + (size_t)(b * 256 + j) * 4096 + nb) = o;
      }
  }
}

// ---------------------------------------------------------------------------
// Radix-4 DIT FFT over 4096 complex points in LDS (swizzled), 256 threads.
// ---------------------------------------------------------------------------
#define FFT_LDS 4368   // swz(4095) = 4365

__device__ inline int swz(int i) { return i + (i >> 4) + (i >> 8); }
__device__ inline int digrev4(int n) {           // 12-bit base-4 digit reverse
  int b = __brev((unsigned)n) >> 20;
  return ((b & 0x555) << 1) | ((b & 0xAAA) >> 1);
}

template<int SIGN>   // -1 forward, +1 inverse
__device__ inline void fft4_stages(cf* X, int tid)
{
  #pragma unroll
  for (int s = 0; s < 6; s++) {
    const int q = 1 << (2 * s);                  // 1,4,16,64,256,1024
    __syncthreads();
    #pragma unroll
    for (int r = 0; r < 4; r++) {
      int t = tid + r * 256;                     // butterfly id 0..1023
      int j = t & (q - 1);
      int base = ((t >> (2 * s)) << (2 * s + 2)) + j;
      cf a = X[swz(base)];
      cf b = X[swz(base + q)];
      cf c = X[swz(base + 2 * q)];
      cf d = X[swz(base + 3 * q)];
      float th = (float)SIGN * 6.283185307179586f * (float)j / (float)(4 * q);
      float s1, c1, s2, c2, s3, c3;
      __sincosf(th, &s1, &c1);
      __sincosf(2.0f * th, &s2, &c2);
      __sincosf(3.0f * th, &s3, &c3);
      cf bt = make_float2(c1 * b.x - s1 * b.y, c1 * b.y + s1 * b.x);
      cf ct = make_float2(c2 * c.x - s2 * c.y, c2 * c.y + s2 * c.x);
      cf dt = make_float2(c3 * d.x - s3 * d.y, c3 * d.y + s3 * d.x);
      cf e0 = make_float2(a.x + ct.x, a.y + ct.y);
      cf e1 = make_float2(a.x - ct.x, a.y - ct.y);
      cf o0 = make_float2(bt.x + dt.x, bt.y + dt.y);
      cf o1 = make_float2(bt.x - dt.x, bt.y - dt.y);
      cf io1 = make_float2(-o1.y, o1.x);         // i*o1
      X[swz(base)]         = make_float2(e0.x + o0.x, e0.y + o0.y);
      X[swz(base + 2 * q)] = make_float2(e0.x - o0.x, e0.y - o0.y);
      if (SIGN < 0) {
        X[swz(base + q)]     = make_float2(e1.x - io1.x, e1.y - io1.y);
        X[swz(base + 3 * q)] = make_float2(e1.x + io1.x, e1.y + io1.y);
      } else {
        X[swz(base + q)]     = make_float2(e1.x + io1.x, e1.y + io1.y);
        X[swz(base + 3 * q)] = make_float2(e1.x - io1.x, e1.y - io1.y);
      }
    }
  }
  __syncthreads();
}

// K2: forward FFT of TWO real columns packed as one complex FFT.
__global__ __launch_bounds__(256) void fft_fwd(
    const float* __restrict__ src_base, cf* __restrict__ dst_base)
{
  __shared__ cf X[FFT_LDS];
  const int c0 = blockIdx.x * 2;
  const float* s0 = src_base + (size_t)c0 * 4096;
  const float* s1 = s0 + 4096;
  const int tid = threadIdx.x;
  #pragma unroll
  for (int i = 0; i < 16; i++) {
    int n = tid + i * 256;
    X[swz(digrev4(n))] = make_float2(s0[n], s1[n]);
  }
  fft4_stages<-1>(X, tid);
  cf* d0 = dst_base + (size_t)c0 * NFREQ;
  cf* d1 = d0 + NFREQ;
  for (int f = tid; f <= 2048; f += 256) {
    cf Zf = X[swz(f)];
    cf Zm = X[swz((4096 - f) & 4095)];
    d0[f] = make_float2(0.5f * (Zf.x + Zm.x), 0.5f * (Zf.y - Zm.y));
    d1[f] = make_float2(0.5f * (Zf.y + Zm.y), 0.5f * (Zm.x - Zf.x));
  }
}

// ---------------------------------------------------------------------------
// K3: circular conv along d via shuffle FFT-32 (conv theorem).
// Block: (bh, 64-f tile). lane&31 = d. Forward DIF (natural->bitrev),
// pointwise in bitrev order, inverse DIT (bitrev->natural). Twiddles
// precomputed per lane per stage (register-resident).
// ---------------------------------------------------------------------------
__device__ inline cf cmul(cf a, cf b) {
  return make_float2(a.x * b.x - a.y * b.y, a.x * b.y + a.y * b.x);
}

__device__ inline cf tw_f(int l, int h) {        // forward twiddle, stage h
  int j = l & (h - 1);
  if (l & h) {
    float sn, cs;
    __sincosf(-3.14159265358979f * (float)j / (float)h, &sn, &cs);
    return make_float2(cs, sn);
  }
  return make_float2(1.0f, 0.0f);
}

template<int H>
__device__ inline cf fwd_stage(cf x, cf w, float sg) { // combine, then twiddle
  float px = __shfl_xor(x.x, H);
  float py = __shfl_xor(x.y, H);
  return cmul(make_float2(px + sg * x.x, py + sg * x.y), w);
}
template<int H>
__device__ inline cf inv_stage(cf x, cf w, float sg) { // twiddle, then combine
  cf t = cmul(x, w);
  float px = __shfl_xor(t.x, H);
  float py = __shfl_xor(t.y, H);
  return make_float2(px + sg * t.x, py + sg * t.y);
}
template<int H>
__device__ inline cf nt_stage(cf x, float sg) {        // no-twiddle stage
  float px = __shfl_xor(x.x, H);
  float py = __shfl_xor(x.y, H);
  return make_float2(px + sg * x.x, py + sg * x.y);
}

__global__ __launch_bounds__(256) void freq_conv(
    cf* __restrict__ Qf, const cf* __restrict__ Kf)
{
  __shared__ cf Qs[32][65];
  __shared__ cf Ks[32][65];
  const int f0 = blockIdx.x * 64;
  const int bh = blockIdx.y;
  const int tid = threadIdx.x;
  const int wave = tid >> 6, lane = tid & 63;
  const int d = lane & 31, hl = lane >> 5;

  #pragma unroll
  for (int i = 0; i < 8; i++) {
    int v = tid + i * 256;
    int e = v >> 6, fl = v & 63;
    int f = f0 + fl;
    if (f < NFREQ) {
      Qs[e][fl] = Qf[(size_t)(bh * 32 + e) * NFREQ + f];
      Ks[e][fl] = Kf[(size_t)(bh * 32 + e) * NFREQ + f];
    } else {
      Qs[e][fl] = make_float2(0.0f, 0.0f);
      Ks[e][fl] = make_float2(0.0f, 0.0f);
    }
  }
  __syncthreads();

  // per-lane twiddles (stage h = 16,8,4,2); inverse = conj(forward)
  const cf w16 = tw_f(d, 16), w8 = tw_f(d, 8), w4 = tw_f(d, 4), w2 = tw_f(d, 2);
  const float s16 = (d & 16) ? -1.0f : 1.0f;
  const float s8  = (d & 8)  ? -1.0f : 1.0f;
  const float s4  = (d & 4)  ? -1.0f : 1.0f;
  const float s2  = (d & 2)  ? -1.0f : 1.0f;
  const float s1  = (d & 1)  ? -1.0f : 1.0f;

  #pragma unroll
  for (int it = 0; it < 8; it++) {
    const int fl = it * 8 + wave * 2 + hl;
    cf q = Qs[d][fl];
    cf k = Ks[d][fl];
    // forward DIF: h = 16, 8, 4, 2 (twiddled), 1 (plain)
    q = fwd_stage<16>(q, w16, s16);  k = fwd_stage<16>(k, w16, s16);
    q = fwd_stage<8>(q, w8, s8);     k = fwd_stage<8>(k, w8, s8);
    q = fwd_stage<4>(q, w4, s4);     k = fwd_stage<4>(k, w4, s4);
    q = fwd_stage<2>(q, w2, s2);     k = fwd_stage<2>(k, w2, s2);
    q = nt_stage<1>(q, s1);          k = nt_stage<1>(k, s1);
    // pointwise (bitrev order on both sides)
    cf c = cmul(q, k);
    // inverse DIT: h = 1 (plain), 2, 4, 8, 16 (conj twiddle before combine)
    c = nt_stage<1>(c, s1);
    c = inv_stage<2>(c, make_float2(w2.x, -w2.y), s2);
    c = inv_stage<4>(c, make_float2(w4.x, -w4.y), s4);
    c = inv_stage<8>(c, make_float2(w8.x, -w8.y), s8);
    c = inv_stage<16>(c, make_float2(w16.x, -w16.y), s16);
    Qs[d][fl] = make_float2(c.x * (1.0f / 32.0f), c.y * (1.0f / 32.0f));
  }
  __syncthreads();

  #pragma unroll
  for (int i = 0; i < 8; i++) {
    int v = tid + i * 256;
    int e = v >> 6, fl = v & 63;
    int f = f0 + fl;
    if (f < NFREQ)
      Qf[(size_t)(bh * 32 + e) * NFREQ + f] = Qs[e][fl];
  }
}

// K4: inverse FFT of TWO hermitian half-spectra packed: Z = C1 + i*C2.
__global__ __launch_bounds__(256) void fft_inv(
    const cf* __restrict__ Cf, float* __restrict__ attn)
{
  __shared__ cf X[FFT_LDS];
  const int c0 = blockIdx.x * 2;
  const cf* s0 = Cf + (size_t)c0 * NFREQ;
  const cf* s1 = s0 + NFREQ;
  const int tid = threadIdx.x;
  for (int f = tid; f <= 2048; f += 256) {
    cf c1 = s0[f];
    cf c2 = s1[f];
    X[swz(digrev4(f))] = make_float2(c1.x - c2.y, c1.y + c2.x);
    if (f != 0 && f != 2048)
      X[swz(digrev4(4096 - f))] = make_float2(c1.x + c2.y, c2.x - c1.y);
  }
  fft4_stages<+1>(X, tid);
  float* d0 = attn + (size_t)c0 * 4096;
  float* d1 = d0 + 4096;
  const float inv = 1.0f / 4096.0f;
  #pragma unroll
  for (int i = 0; i < 16; i++) {
    int n = tid + i * 256;
    cf z = X[swz(n)];
    d0[n] = z.x * inv;
    d1[n] = z.y * inv;
  }
}

// ---------------------------------------------------------------------------
// K5: softmax over d (32) + value gate + residual + LayerNorm(256)
// ---------------------------------------------------------------------------
__global__ __launch_bounds__(256) void finalize_kernel(
    const float* __restrict__ attn, const float* __restrict__ VL,
    const float* __restrict__ vin, const float* __restrict__ gamma,
    const float* __restrict__ beta, float* __restrict__ out)
{
  __shared__ float At[256][33];
  const int n0 = blockIdx.x * 32;
  const int b = blockIdx.y;
  const int tid = threadIdx.x;
  #pragma unroll
  for (int i = 0; i < 32; i++) {
    int v = tid + i * 256;
    int hd = v >> 5, nn = v & 31;
    At[hd][nn] = attn[(size_t)(b * 256 + hd) * 4096 + n0 + nn];
  }
  __syncthreads();
  const int wave = tid >> 6, lane = tid & 63;
  float g[4], bt[4];
  #pragma unroll
  for (int r = 0; r < 4; r++) { g[r] = gamma[64 * r + lane]; bt[r] = beta[64 * r + lane]; }

  for (int t = 0; t < 8; t++) {
    const int nn = wave * 8 + t;
    const int n = n0 + nn;
    float p[4];
    #pragma unroll
    for (int r = 0; r < 4; r++) {
      float a = At[64 * r + lane][nn];
      float mx = a;
      #pragma unroll
      for (int off = 16; off >= 1; off >>= 1) mx = fmaxf(mx, __shfl_xor(mx, off, 32));
      float e = __expf(a - mx);
      float s = e;
      #pragma unroll
      for (int off = 16; off >= 1; off >>= 1) s += __shfl_xor(s, off, 32);
      p[r] = e / s;
    }
    const size_t base = ((size_t)b * 4096 + n) * 256 + lane;
    float o[4];
    float s1 = 0.0f, s2 = 0.0f;
    #pragma unroll
    for (int r = 0; r < 4; r++) {
      o[r] = VL[base + 64 * r] * p[r] + vin[base + 64 * r];
      s1 += o[r];
      s2 += o[r] * o[r];
    }
    #pragma unroll
    for (int off = 32; off >= 1; off >>= 1) {
      s1 += __shfl_xor(s1, off, 64);
      s2 += __shfl_xor(s2, off, 64);
    }
    float mu = s1 * (1.0f / 256.0f);
    float var = s2 * (1.0f / 256.0f) - mu * mu;
    float rs = rsqrtf(var + 1e-5f);
    #pragma unroll
    for (int r = 0; r < 4; r++)
      out[base + 64 * r] = (o[r] - mu) * rs * g[r] + bt[r];
  }
}

// ---------------------------------------------------------------------------
extern "C" void kernel_launch(void* const* d_in, const int* in_sizes, int n_in,
                              void* d_out, int out_size, void* d_ws, size_t ws_size,
                              hipStream_t stream)
{
  const float* q  = (const float*)d_in[0];
  const float* k  = (const float*)d_in[1];
  const float* v  = (const float*)d_in[2];
  const float* Wq = (const float*)d_in[3];
  const float* bq = (const float*)d_in[4];
  const float* Wk = (const float*)d_in[5];
  const float* bk = (const float*)d_in[6];
  const float* Wv = (const float*)d_in[7];
  const float* bv = (const float*)d_in[8];
  const float* ln_gamma = (const float*)d_in[9];
  const float* ln_beta  = (const float*)d_in[10];
  float* out = (float*)d_out;

  float* ws = (float*)d_ws;
  float* QL = ws;                               // [2048][4096]
  float* KL = QL + (size_t)8388608;             // [2048][4096]
  float* VL = KL + (size_t)8388608;             // [32768][256]
  cf* Qf = (cf*)(VL + (size_t)8388608);         // [2048][2049] complex
  cf* Kf = Qf + (size_t)2048 * NFREQ;           // [2048][2049] complex
  float* attn = QL;                             // reuse QL after fwd FFT

  gemm_proj<<<dim3(256, 4), 256, 0, stream>>>(q, Wq, bq, QL, 0);
  gemm_proj<<<dim3(256, 4), 256, 0, stream>>>(k, Wk, bk, KL, 1);
  gemm_proj<<<dim3(256, 4), 256, 0, stream>>>(v, Wv, bv, VL, 2);

  fft_fwd<<<1024, 256, 0, stream>>>(QL, Qf);
  fft_fwd<<<1024, 256, 0, stream>>>(KL, Kf);

  freq_conv<<<dim3(33, 64), 256, 0, stream>>>(Qf, Kf);

  fft_inv<<<1024, 256, 0, stream>>>(Qf, attn);

  finalize_kernel<<<dim3(128, 8), 256, 0, stream>>>(attn, VL, v, ln_gamma,
                                                    ln_beta, out);
}

// Round 6
// 293.802 us; speedup vs baseline: 1.1066x; 1.1066x over previous
//
#include <hip/hip_runtime.h>

#define NFREQ 2049   // 4096/2 + 1

using cf = float2;
typedef __attribute__((ext_vector_type(8))) short short8;
typedef __attribute__((ext_vector_type(4))) float floatx4;

__device__ inline unsigned short bf16_rne(float x) {
  unsigned u = __float_as_uint(x);
  unsigned r = u + 0x7FFFu + ((u >> 16) & 1u);
  return (unsigned short)(r >> 16);
}
__device__ inline float bf16_to_f(unsigned short h) {
  return __uint_as_float(((unsigned)h) << 16);
}
__device__ inline cf cmul(cf a, cf b) {
  return make_float2(a.x * b.x - a.y * b.y, a.x * b.y + a.y * b.x);
}
__device__ inline cf cadd(cf a, cf b) { return make_float2(a.x + b.x, a.y + b.y); }
__device__ inline cf csub(cf a, cf b) { return make_float2(a.x - b.x, a.y - b.y); }

// ---------------------------------------------------------------------------
// K1: 3 projection GEMMs in ONE dispatch (blockIdx.z selects q/k/v).
//   C = X @ W^T + b, X: [32768,256], W: [256,256].
// z=0/1 (Q/K): dst[(b*256 + j)*4096 + n] transposed; z=2 (V): dst[m*256+j].
// Split-bf16 MFMA (3 passes), tile 128m x 64j, K-chunk 32.
// ---------------------------------------------------------------------------
__global__ __launch_bounds__(256, 4) void gemm_proj(
    const float* __restrict__ Xq, const float* __restrict__ Wq, const float* __restrict__ bq,
    const float* __restrict__ Xk, const float* __restrict__ Wk, const float* __restrict__ bk,
    const float* __restrict__ Xv, const float* __restrict__ Wv, const float* __restrict__ bv,
    float* __restrict__ dq, float* __restrict__ dk, float* __restrict__ dv)
{
  const int z = blockIdx.z;
  const float* X = (z == 0) ? Xq : (z == 1) ? Xk : Xv;
  const float* W = (z == 0) ? Wq : (z == 1) ? Wk : Wv;
  const float* bias = (z == 0) ? bq : (z == 1) ? bk : bv;
  float* dst = (z == 0) ? dq : (z == 1) ? dk : dv;

  __shared__ __align__(16) unsigned short sm[12416];
  unsigned short* sAhi = sm;            // 4*129*8 = 4128
  unsigned short* sAlo = sm + 4128;
  unsigned short* sBhi = sm + 8256;     // 4*65*8  = 2080
  unsigned short* sBlo = sm + 10336;

  const int tid = threadIdx.x;
  const int m0 = blockIdx.x * 128;
  const int j0 = blockIdx.y * 64;
  const int wave = tid >> 6, lane = tid & 63;
  const int wm = wave & 1, wj = wave >> 1;
  const int lm = lane & 15, quad = lane >> 4;

  floatx4 acc[4][2] = {};

  for (int k0 = 0; k0 < 256; k0 += 32) {
    float4 xa[4], wb[2];
    #pragma unroll
    for (int r = 0; r < 4; r++) {
      int v = tid + r * 256;
      int row = v >> 3, c4 = (v & 7) * 4;
      xa[r] = *(const float4*)(X + (size_t)(m0 + row) * 256 + k0 + c4);
    }
    #pragma unroll
    for (int r = 0; r < 2; r++) {
      int v = tid + r * 256;
      int row = v >> 3, c4 = (v & 7) * 4;
      wb[r] = *(const float4*)(W + (size_t)(j0 + row) * 256 + k0 + c4);
    }
    __syncthreads();
    #pragma unroll
    for (int r = 0; r < 4; r++) {
      int v = tid + r * 256;
      int row = v >> 3, c4 = (v & 7) * 4;
      int q = c4 >> 3, off = c4 & 7;
      float f[4] = {xa[r].x, xa[r].y, xa[r].z, xa[r].w};
      unsigned short h[4], l[4];
      #pragma unroll
      for (int i = 0; i < 4; i++) {
        h[i] = bf16_rne(f[i]);
        l[i] = bf16_rne(f[i] - bf16_to_f(h[i]));
      }
      int idx = ((q * 129 + row) << 3) + off;
      *(uint2*)&sAhi[idx] = make_uint2((unsigned)h[0] | ((unsigned)h[1] << 16),
                                       (unsigned)h[2] | ((unsigned)h[3] << 16));
      *(uint2*)&sAlo[idx] = make_uint2((unsigned)l[0] | ((unsigned)l[1] << 16),
                                       (unsigned)l[2] | ((unsigned)l[3] << 16));
    }
    #pragma unroll
    for (int r = 0; r < 2; r++) {
      int v = tid + r * 256;
      int row = v >> 3, c4 = (v & 7) * 4;
      int q = c4 >> 3, off = c4 & 7;
      float f[4] = {wb[r].x, wb[r].y, wb[r].z, wb[r].w};
      unsigned short h[4], l[4];
      #pragma unroll
      for (int i = 0; i < 4; i++) {
        h[i] = bf16_rne(f[i]);
        l[i] = bf16_rne(f[i] - bf16_to_f(h[i]));
      }
      int idx = ((q * 65 + row) << 3) + off;
      *(uint2*)&sBhi[idx] = make_uint2((unsigned)h[0] | ((unsigned)h[1] << 16),
                                       (unsigned)h[2] | ((unsigned)h[3] << 16));
      *(uint2*)&sBlo[idx] = make_uint2((unsigned)l[0] | ((unsigned)l[1] << 16),
                                       (unsigned)l[2] | ((unsigned)l[3] << 16));
    }
    __syncthreads();

    short8 ahi[4], alo[4], bhi[2], blo[2];
    #pragma unroll
    for (int mf = 0; mf < 4; mf++) {
      int row = wm * 64 + mf * 16 + lm;
      int idx = ((quad * 129 + row) << 3);
      ahi[mf] = *(const short8*)&sAhi[idx];
      alo[mf] = *(const short8*)&sAlo[idx];
    }
    #pragma unroll
    for (int jf = 0; jf < 2; jf++) {
      int row = wj * 32 + jf * 16 + lm;
      int idx = ((quad * 65 + row) << 3);
      bhi[jf] = *(const short8*)&sBhi[idx];
      blo[jf] = *(const short8*)&sBlo[idx];
    }
    #pragma unroll
    for (int mf = 0; mf < 4; mf++)
      #pragma unroll
      for (int jf = 0; jf < 2; jf++) {
        acc[mf][jf] = __builtin_amdgcn_mfma_f32_16x16x32_bf16(
            ahi[mf], bhi[jf], acc[mf][jf], 0, 0, 0);
        acc[mf][jf] = __builtin_amdgcn_mfma_f32_16x16x32_bf16(
            ahi[mf], blo[jf], acc[mf][jf], 0, 0, 0);
        acc[mf][jf] = __builtin_amdgcn_mfma_f32_16x16x32_bf16(
            alo[mf], bhi[jf], acc[mf][jf], 0, 0, 0);
      }
  }

  #pragma unroll
  for (int jf = 0; jf < 2; jf++) {
    float bj = bias[j0 + wj * 32 + jf * 16 + lm];
    #pragma unroll
    for (int mf = 0; mf < 4; mf++)
      #pragma unroll
      for (int r = 0; r < 4; r++)
        acc[mf][jf][r] += bj;
  }

  if (z == 2) {
    #pragma unroll
    for (int mf = 0; mf < 4; mf++)
      #pragma unroll
      for (int jf = 0; jf < 2; jf++) {
        int j = j0 + wj * 32 + jf * 16 + lm;
        int mb = m0 + wm * 64 + mf * 16 + quad * 4;
        #pragma unroll
        for (int r = 0; r < 4; r++)
          dst[(size_t)(mb + r) * 256 + j] = acc[mf][jf][r];
      }
  } else {
    const int b = m0 >> 12;
    const int n0 = m0 & 4095;
    #pragma unroll
    for (int mf = 0; mf < 4; mf++)
      #pragma unroll
      for (int jf = 0; jf < 2; jf++) {
        int j = j0 + wj * 32 + jf * 16 + lm;
        int nb = n0 + wm * 64 + mf * 16 + quad * 4;
        float4 o = make_float4(acc[mf][jf][0], acc[mf][jf][1],
                               acc[mf][jf][2], acc[mf][jf][3]);
        *(float4*)(dst + (size_t)(b * 256 + j) * 4096 + nb) = o;
      }
  }
}

// ---------------------------------------------------------------------------
// Radix-8 DIT FFT over 4096 complex points in LDS (swizzled), 256 threads.
// 4 stages (q = 1,8,64,512), input base-8 digit-reversed, output natural.
// Swizzle spreads all per-instruction lane patterns to <=4-way banking.
// ---------------------------------------------------------------------------
#define FFT_LDS 4376   // swz(4095) = 4372

__device__ inline int swz(int i) { return i + (i >> 4) + (i >> 8) + (i >> 9); }
__device__ inline int digrev8(int n) {   // 12 bits = 4 octal digits reversed
  return ((n & 7) << 9) | (((n >> 3) & 7) << 6) | (((n >> 6) & 7) << 3) | ((n >> 9) & 7);
}

template<int SIGN>   // -1 forward, +1 inverse
__device__ inline void fft8_stages(cf* X, int tid)
{
  const float C = 0.70710678118654752f;
  const float sg = (float)SIGN;
  #pragma unroll
  for (int s = 0; s < 4; s++) {
    const int q = 1 << (3 * s);                  // 1, 8, 64, 512
    __syncthreads();
    #pragma unroll
    for (int r = 0; r < 2; r++) {
      int t = tid + r * 256;                     // butterfly id 0..511
      int j = t & (q - 1);
      int base = ((t >> (3 * s)) << (3 * s + 3)) + j;
      cf x[8];
      #pragma unroll
      for (int l = 0; l < 8; l++) x[l] = X[swz(base + l * q)];
      if (s > 0) {
        // twiddle x[l] *= W^(j*l), W = e^{SIGN*2pi i/(8q)}; powers iteratively
        float a = sg * 6.283185307179586f * (float)j / (float)(8 * q);
        float sn, cs;
        __sincosf(a, &sn, &cs);
        cf w1 = make_float2(cs, sn);
        cf w = w1;
        #pragma unroll
        for (int l = 1; l < 8; l++) {
          x[l] = cmul(x[l], w);
          if (l < 7) w = cmul(w, w1);
        }
      }
      // 8-point DFT, root e^{sg*2pi i/8}
      cf u0 = cadd(x[0], x[4]), v0 = csub(x[0], x[4]);
      cf u1 = cadd(x[1], x[5]), v1 = csub(x[1], x[5]);
      cf u2 = cadd(x[2], x[6]), v2 = csub(x[2], x[6]);
      cf u3 = cadd(x[3], x[7]), v3 = csub(x[3], x[7]);
      // odd pre-rotations by c8^l, c8 = C*(1 + i*sg)
      cf w1v = make_float2(C * (v1.x - sg * v1.y), C * (v1.y + sg * v1.x));
      cf w2v = make_float2(-sg * v2.y, sg * v2.x);
      cf w3v = make_float2(C * (-v3.x - sg * v3.y), C * (sg * v3.x - v3.y));
      // DFT4(u) -> even outputs
      cf e0 = cadd(u0, u2), e1 = csub(u0, u2);
      cf o0 = cadd(u1, u3), o1 = csub(u1, u3);
      cf F0 = cadd(e0, o0), F4 = csub(e0, o0);
      cf F2 = make_float2(e1.x - sg * o1.y, e1.y + sg * o1.x);
      cf F6 = make_float2(e1.x + sg * o1.y, e1.y - sg * o1.x);
      // DFT4(w) -> odd outputs
      cf e0b = cadd(v0, w2v), e1b = csub(v0, w2v);
      cf o0b = cadd(w1v, w3v), o1b = csub(w1v, w3v);
      cf F1 = cadd(e0b, o0b), F5 = csub(e0b, o0b);
      cf F3 = make_float2(e1b.x - sg * o1b.y, e1b.y + sg * o1b.x);
      cf F7 = make_float2(e1b.x + sg * o1b.y, e1b.y - sg * o1b.x);
      X[swz(base + 0 * q)] = F0;
      X[swz(base + 1 * q)] = F1;
      X[swz(base + 2 * q)] = F2;
      X[swz(base + 3 * q)] = F3;
      X[swz(base + 4 * q)] = F4;
      X[swz(base + 5 * q)] = F5;
      X[swz(base + 6 * q)] = F6;
      X[swz(base + 7 * q)] = F7;
    }
  }
  __syncthreads();
}

// K2: forward FFT of TWO real columns packed as one complex FFT.
// grid.y: 0 = QL->Qf, 1 = KL->Kf (merged dispatch).
__global__ __launch_bounds__(256) void fft_fwd(
    const float* __restrict__ srcQ, cf* __restrict__ dstQ,
    const float* __restrict__ srcK, cf* __restrict__ dstK)
{
  __shared__ cf X[FFT_LDS];
  const float* src_base = blockIdx.y ? srcK : srcQ;
  cf* dst_base = blockIdx.y ? dstK : dstQ;
  const int c0 = blockIdx.x * 2;
  const float* s0 = src_base + (size_t)c0 * 4096;
  const float* s1 = s0 + 4096;
  const int tid = threadIdx.x;
  #pragma unroll
  for (int i = 0; i < 16; i++) {
    int n = tid + i * 256;
    X[swz(digrev8(n))] = make_float2(s0[n], s1[n]);
  }
  fft8_stages<-1>(X, tid);
  cf* d0 = dst_base + (size_t)c0 * NFREQ;
  cf* d1 = d0 + NFREQ;
  for (int f = tid; f <= 2048; f += 256) {
    cf Zf = X[swz(f)];
    cf Zm = X[swz((4096 - f) & 4095)];
    d0[f] = make_float2(0.5f * (Zf.x + Zm.x), 0.5f * (Zf.y - Zm.y));
    d1[f] = make_float2(0.5f * (Zf.y + Zm.y), 0.5f * (Zm.x - Zf.x));
  }
}

// ---------------------------------------------------------------------------
// K3: circular conv along d via shuffle FFT-32 (conv theorem).
// ---------------------------------------------------------------------------
__device__ inline cf tw_f(int l, int h) {        // forward twiddle, stage h
  int j = l & (h - 1);
  if (l & h) {
    float sn, cs;
    __sincosf(-3.14159265358979f * (float)j / (float)h, &sn, &cs);
    return make_float2(cs, sn);
  }
  return make_float2(1.0f, 0.0f);
}

template<int H>
__device__ inline cf fwd_stage(cf x, cf w, float sg) { // combine, then twiddle
  float px = __shfl_xor(x.x, H);
  float py = __shfl_xor(x.y, H);
  return cmul(make_float2(px + sg * x.x, py + sg * x.y), w);
}
template<int H>
__device__ inline cf inv_stage(cf x, cf w, float sg) { // twiddle, then combine
  cf t = cmul(x, w);
  float px = __shfl_xor(t.x, H);
  float py = __shfl_xor(t.y, H);
  return make_float2(px + sg * t.x, py + sg * t.y);
}
template<int H>
__device__ inline cf nt_stage(cf x, float sg) {        // no-twiddle stage
  float px = __shfl_xor(x.x, H);
  float py = __shfl_xor(x.y, H);
  return make_float2(px + sg * x.x, py + sg * x.y);
}

__global__ __launch_bounds__(256) void freq_conv(
    cf* __restrict__ Qf, const cf* __restrict__ Kf)
{
  __shared__ cf Qs[32][65];
  __shared__ cf Ks[32][65];
  const int f0 = blockIdx.x * 64;
  const int bh = blockIdx.y;
  const int tid = threadIdx.x;
  const int wave = tid >> 6, lane = tid & 63;
  const int d = lane & 31, hl = lane >> 5;

  #pragma unroll
  for (int i = 0; i < 8; i++) {
    int v = tid + i * 256;
    int e = v >> 6, fl = v & 63;
    int f = f0 + fl;
    if (f < NFREQ) {
      Qs[e][fl] = Qf[(size_t)(bh * 32 + e) * NFREQ + f];
      Ks[e][fl] = Kf[(size_t)(bh * 32 + e) * NFREQ + f];
    } else {
      Qs[e][fl] = make_float2(0.0f, 0.0f);
      Ks[e][fl] = make_float2(0.0f, 0.0f);
    }
  }
  __syncthreads();

  const cf w16 = tw_f(d, 16), w8 = tw_f(d, 8), w4 = tw_f(d, 4), w2 = tw_f(d, 2);
  const float s16 = (d & 16) ? -1.0f : 1.0f;
  const float s8  = (d & 8)  ? -1.0f : 1.0f;
  const float s4  = (d & 4)  ? -1.0f : 1.0f;
  const float s2  = (d & 2)  ? -1.0f : 1.0f;
  const float s1  = (d & 1)  ? -1.0f : 1.0f;

  #pragma unroll
  for (int it = 0; it < 8; it++) {
    const int fl = it * 8 + wave * 2 + hl;
    cf q = Qs[d][fl];
    cf k = Ks[d][fl];
    q = fwd_stage<16>(q, w16, s16);  k = fwd_stage<16>(k, w16, s16);
    q = fwd_stage<8>(q, w8, s8);     k = fwd_stage<8>(k, w8, s8);
    q = fwd_stage<4>(q, w4, s4);     k = fwd_stage<4>(k, w4, s4);
    q = fwd_stage<2>(q, w2, s2);     k = fwd_stage<2>(k, w2, s2);
    q = nt_stage<1>(q, s1);          k = nt_stage<1>(k, s1);
    cf c = cmul(q, k);
    c = nt_stage<1>(c, s1);
    c = inv_stage<2>(c, make_float2(w2.x, -w2.y), s2);
    c = inv_stage<4>(c, make_float2(w4.x, -w4.y), s4);
    c = inv_stage<8>(c, make_float2(w8.x, -w8.y), s8);
    c = inv_stage<16>(c, make_float2(w16.x, -w16.y), s16);
    Qs[d][fl] = make_float2(c.x * (1.0f / 32.0f), c.y * (1.0f / 32.0f));
  }
  __syncthreads();

  #pragma unroll
  for (int i = 0; i < 8; i++) {
    int v = tid + i * 256;
    int e = v >> 6, fl = v & 63;
    int f = f0 + fl;
    if (f < NFREQ)
      Qf[(size_t)(bh * 32 + e) * NFREQ + f] = Qs[e][fl];
  }
}

// K4: inverse FFT of TWO hermitian half-spectra packed: Z = C1 + i*C2.
__global__ __launch_bounds__(256) void fft_inv(
    const cf* __restrict__ Cf, float* __restrict__ attn)
{
  __shared__ cf X[FFT_LDS];
  const int c0 = blockIdx.x * 2;
  const cf* s0 = Cf + (size_t)c0 * NFREQ;
  const cf* s1 = s0 + NFREQ;
  const int tid = threadIdx.x;
  for (int f = tid; f <= 2048; f += 256) {
    cf c1 = s0[f];
    cf c2 = s1[f];
    X[swz(digrev8(f))] = make_float2(c1.x - c2.y, c1.y + c2.x);
    if (f != 0 && f != 2048)
      X[swz(digrev8(4096 - f))] = make_float2(c1.x + c2.y, c2.x - c1.y);
  }
  fft8_stages<+1>(X, tid);
  float* d0 = attn + (size_t)c0 * 4096;
  float* d1 = d0 + 4096;
  const float inv = 1.0f / 4096.0f;
  #pragma unroll
  for (int i = 0; i < 16; i++) {
    int n = tid + i * 256;
    cf z = X[swz(n)];
    d0[n] = z.x * inv;
    d1[n] = z.y * inv;
  }
}

// ---------------------------------------------------------------------------
// K5: softmax over d (32) + value gate + residual + LayerNorm(256)
// ---------------------------------------------------------------------------
__global__ __launch_bounds__(256) void finalize_kernel(
    const float* __restrict__ attn, const float* __restrict__ VL,
    const float* __restrict__ vin, const float* __restrict__ gamma,
    const float* __restrict__ beta, float* __restrict__ out)
{
  __shared__ float At[256][33];
  const int n0 = blockIdx.x * 32;
  const int b = blockIdx.y;
  const int tid = threadIdx.x;
  #pragma unroll
  for (int i = 0; i < 32; i++) {
    int v = tid + i * 256;
    int hd = v >> 5, nn = v & 31;
    At[hd][nn] = attn[(size_t)(b * 256 + hd) * 4096 + n0 + nn];
  }
  __syncthreads();
  const int wave = tid >> 6, lane = tid & 63;
  float g[4], bt[4];
  #pragma unroll
  for (int r = 0; r < 4; r++) { g[r] = gamma[64 * r + lane]; bt[r] = beta[64 * r + lane]; }

  for (int t = 0; t < 8; t++) {
    const int nn = wave * 8 + t;
    const int n = n0 + nn;
    float p[4];
    #pragma unroll
    for (int r = 0; r < 4; r++) {
      float a = At[64 * r + lane][nn];
      float mx = a;
      #pragma unroll
      for (int off = 16; off >= 1; off >>= 1) mx = fmaxf(mx, __shfl_xor(mx, off, 32));
      float e = __expf(a - mx);
      float s = e;
      #pragma unroll
      for (int off = 16; off >= 1; off >>= 1) s += __shfl_xor(s, off, 32);
      p[r] = e / s;
    }
    const size_t base = ((size_t)b * 4096 + n) * 256 + lane;
    float o[4];
    float s1 = 0.0f, s2 = 0.0f;
    #pragma unroll
    for (int r = 0; r < 4; r++) {
      o[r] = VL[base + 64 * r] * p[r] + vin[base + 64 * r];
      s1 += o[r];
      s2 += o[r] * o[r];
    }
    #pragma unroll
    for (int off = 32; off >= 1; off >>= 1) {
      s1 += __shfl_xor(s1, off, 64);
      s2 += __shfl_xor(s2, off, 64);
    }
    float mu = s1 * (1.0f / 256.0f);
    float var = s2 * (1.0f / 256.0f) - mu * mu;
    float rs = rsqrtf(var + 1e-5f);
    #pragma unroll
    for (int r = 0; r < 4; r++)
      out[base + 64 * r] = (o[r] - mu) * rs * g[r] + bt[r];
  }
}

// ---------------------------------------------------------------------------
extern "C" void kernel_launch(void* const* d_in, const int* in_sizes, int n_in,
                              void* d_out, int out_size, void* d_ws, size_t ws_size,
                              hipStream_t stream)
{
  const float* q  = (const float*)d_in[0];
  const float* k  = (const float*)d_in[1];
  const float* v  = (const float*)d_in[2];
  const float* Wq = (const float*)d_in[3];
  const float* bq = (const float*)d_in[4];
  const float* Wk = (const float*)d_in[5];
  const float* bk = (const float*)d_in[6];
  const float* Wv = (const float*)d_in[7];
  const float* bv = (const float*)d_in[8];
  const float* ln_gamma = (const float*)d_in[9];
  const float* ln_beta  = (const float*)d_in[10];
  float* out = (float*)d_out;

  float* ws = (float*)d_ws;
  float* QL = ws;                               // [2048][4096]
  float* KL = QL + (size_t)8388608;             // [2048][4096]
  float* VL = KL + (size_t)8388608;             // [32768][256]
  cf* Qf = (cf*)(VL + (size_t)8388608);         // [2048][2049] complex
  cf* Kf = Qf + (size_t)2048 * NFREQ;           // [2048][2049] complex
  float* attn = QL;                             // reuse QL after fwd FFT

  gemm_proj<<<dim3(256, 4, 3), 256, 0, stream>>>(q, Wq, bq, k, Wk, bk, v, Wv, bv,
                                                 QL, KL, VL);

  fft_fwd<<<dim3(1024, 2), 256, 0, stream>>>(QL, Qf, KL, Kf);

  freq_conv<<<dim3(33, 64), 256, 0, stream>>>(Qf, Kf);

  fft_inv<<<1024, 256, 0, stream>>>(Qf, attn);

  finalize_kernel<<<dim3(128, 8), 256, 0, stream>>>(attn, VL, v, ln_gamma,
                                                    ln_beta, out);
}